// Round 2
// baseline (1193.483 us; speedup 1.0000x reference)
//
#include <hip/hip_runtime.h>
#include <math.h>

#define NANCH 16128      // 64*64*3 + 32*32*3 + 16*16*3
#define NB    16
#define NDET  100
#define SCORE_TH 0.25f
#define IOU_TH   0.5f
#define IMGSZ    512.0f

#define DEC_THREADS 256
#define DEC_ANCH    192               // anchors per decode block (divides 12288/3072/768)
#define DEC_BLOCKS_PER_IMG 84         // 16128 / 192
#define DEC_DW4     (DEC_ANCH * 85 / 4)   // 4080 float4 = 63.75 KB LDS

#define NMS_THREADS 1024
#define SLOTS 16

__device__ __constant__ float c_anchors[18] = {
    12.f,16.f, 19.f,36.f, 40.f,28.f,
    36.f,75.f, 76.f,55.f, 72.f,146.f,
    142.f,110.f, 192.f,243.f, 459.f,401.f
};

__device__ __forceinline__ float sigmoidf_(float x) {
    return 1.0f / (1.0f + expf(-x));
}

__global__ __launch_bounds__(DEC_THREADS)
void decode_kernel(const float* __restrict__ p0,
                   const float* __restrict__ p1,
                   const float* __restrict__ p2,
                   float4* __restrict__ boxes,
                   float* __restrict__ scores,
                   unsigned char* __restrict__ classes) {
    __shared__ float4 lds4[DEC_DW4];

    int blk = blockIdx.x;
    int b   = blk / DEC_BLOCKS_PER_IMG;
    int seg = blk % DEC_BLOCKS_PER_IMG;

    const float* src; int S, lgS, scale, loc;
    float stride;
    if (seg < 64)      { scale = 0; S = 64; lgS = 6; stride = 8.f;  src = p0; loc = seg * DEC_ANCH; }
    else if (seg < 80) { scale = 1; S = 32; lgS = 5; stride = 16.f; src = p1; loc = seg * DEC_ANCH - 12288; }
    else               { scale = 2; S = 16; lgS = 4; stride = 32.f; src = p2; loc = seg * DEC_ANCH - 15360; }

    // coalesced float4 staging: base offset is a multiple of 16320 floats -> 16B aligned
    const float4* s4 = (const float4*)(src + ((size_t)b * (S * S * 3) + loc) * 85);
    {
        int j = threadIdx.x;
        #pragma unroll
        for (int r = 0; r < 15; ++r, j += DEC_THREADS) lds4[j] = s4[j];
        if (j < DEC_DW4) lds4[j] = s4[j];
    }
    __syncthreads();

    int t = threadIdx.x;
    if (t < DEC_ANCH) {
        const float* p = (const float*)lds4 + t * 85;   // stride 85 (odd) -> conflict-free
        int local = loc + t;
        int a    = local % 3;
        int cell = local / 3;
        int gj   = cell & (S - 1);
        int gi   = cell >> lgS;

        float tx = p[0], ty = p[1], tw = p[2], th = p[3], tobj = p[4];

        float bestl = p[5];
        int   bc    = 0;
        #pragma unroll 8
        for (int c = 1; c < 80; ++c) {
            float v = p[5 + c];
            if (v > bestl) { bestl = v; bc = c; }
        }

        float bx = ((sigmoidf_(tx) * 2.0f - 0.5f) + (float)gj) * stride;
        float by = ((sigmoidf_(ty) * 2.0f - 0.5f) + (float)gi) * stride;
        float sw = sigmoidf_(tw) * 2.0f; sw = sw * sw;
        float sh = sigmoidf_(th) * 2.0f; sh = sh * sh;
        float aw = c_anchors[scale * 6 + a * 2];
        float ah = c_anchors[scale * 6 + a * 2 + 1];
        float bw = sw * aw;
        float bh = sh * ah;

        bx = fminf(fmaxf(bx, 0.f), IMGSZ);
        by = fminf(fmaxf(by, 0.f), IMGSZ);
        bw = fminf(fmaxf(bw, 0.f), IMGSZ);
        bh = fminf(fmaxf(bh, 0.f), IMGSZ);

        float score = sigmoidf_(tobj) * sigmoidf_(bestl);
        score = (score >= SCORE_TH) ? score : -1.0f;

        size_t g = (size_t)b * NANCH + seg * DEC_ANCH + t;
        boxes[g]   = make_float4(bx, by, bw, bh);
        scores[g]  = score;
        classes[g] = (unsigned char)bc;
    }
}

__global__ __launch_bounds__(NMS_THREADS, 4)   // min 4 waves/SIMD -> 128 VGPR cap
void nms_kernel(const float4* __restrict__ boxes,
                const float*  __restrict__ scores,
                const unsigned char* __restrict__ classes,
                float* __restrict__ out) {
    int b    = blockIdx.x;
    int tid  = threadIdx.x;
    int lane = tid & 63;
    int wave = tid >> 6;

    const float4*        bb = boxes   + (size_t)b * NANCH;
    const float*         ss = scores  + (size_t)b * NANCH;
    const unsigned char* cc = classes + (size_t)b * NANCH;
    float* o = out + (size_t)b * NDET * 6;

    __shared__ unsigned long long red_k[16];
    __shared__ float bcast[4];
    __shared__ float dets[NDET * 6];

    // thread t owns contiguous anchors [t*16, t*16+16) -> spatially local -> tight AABB
    float  sc[SLOTS];
    float4 bx[SLOTS];
    unsigned int clpk[4] = {0u, 0u, 0u, 0u};
    int  base = tid * SLOTS;
    bool own  = (base < NANCH);           // tid < 1008

    float gminx = 1e30f, gminy = 1e30f, gmaxx = -1e30f, gmaxy = -1e30f;
    #pragma unroll
    for (int k = 0; k < SLOTS; ++k) {
        if (own) {
            sc[k] = ss[base + k];
            bx[k] = bb[base + k];
            clpk[k >> 2] |= ((unsigned int)cc[base + k]) << ((k & 3) * 8);
            if (sc[k] > 0.0f) {   // only live boxes can ever be picked -> AABB over live only
                gminx = fminf(gminx, bx[k].x - bx[k].z * 0.5f);
                gmaxx = fmaxf(gmaxx, bx[k].x + bx[k].z * 0.5f);
                gminy = fminf(gminy, bx[k].y - bx[k].w * 0.5f);
                gmaxy = fmaxf(gmaxy, bx[k].y + bx[k].w * 0.5f);
            }
        } else {
            sc[k] = -1.0f;
            bx[k] = make_float4(0.f, 0.f, 0.f, 0.f);
        }
    }

    float v  = 0.0f;   // cached per-thread max (0 = none)
    int   vi = 0;
    bool  dirty = true;

    for (int it = 0; it < NDET; ++it) {
        // --- per-thread argmax, skipped when no owned score changed ---
        if (dirty) {
            v = 0.0f; vi = 0;
            #pragma unroll
            for (int k = 0; k < SLOTS; ++k) {
                if (sc[k] > v) { v = sc[k]; vi = base + k; }   // strict > = first occurrence
            }
            dirty = false;
        }
        // pack (score, ~idx): u64 max == lexicographic (max score, min idx)
        unsigned long long key = (v > 0.0f)
            ? ((unsigned long long)__float_as_uint(v) << 32) |
              (unsigned long long)(0xFFFFFFFFu - (unsigned int)vi)
            : 0ull;

        #pragma unroll
        for (int off = 32; off; off >>= 1) {
            unsigned long long ok = __shfl_xor(key, off);
            if (ok > key) key = ok;
        }
        if (lane == 0) red_k[wave] = key;
        __syncthreads();                               // barrier A

        // all waves redundantly reduce the 16 wave maxima (kills the 2nd barrier)
        unsigned long long bk = red_k[lane & 15];
        #pragma unroll
        for (int off = 8; off; off >>= 1) {
            unsigned long long ok = __shfl_xor(bk, off);
            if (ok > bk) bk = ok;
        }

        if (bk == 0ull) {                              // nothing left: zero-fill, done
            for (int z = it * 6 + tid; z < NDET * 6; z += NMS_THREADS) dets[z] = 0.0f;
            break;
        }
        float bestV = __uint_as_float((unsigned int)(bk >> 32));
        int   bestI = (int)(0xFFFFFFFFu - (unsigned int)bk);

        // owner publishes box (LDS) + detection row (LDS), clears its slot
        if (own && bestI >= base && bestI < base + SLOTS) {
            #pragma unroll
            for (int k = 0; k < SLOTS; ++k) {
                if (base + k == bestI) {
                    bcast[0] = bx[k].x; bcast[1] = bx[k].y;
                    bcast[2] = bx[k].z; bcast[3] = bx[k].w;
                    dets[it * 6 + 0] = bx[k].x;
                    dets[it * 6 + 1] = bx[k].y;
                    dets[it * 6 + 2] = bx[k].z;
                    dets[it * 6 + 3] = bx[k].w;
                    dets[it * 6 + 4] = bestV;
                    dets[it * 6 + 5] = (float)((clpk[k >> 2] >> ((k & 3) * 8)) & 255u);
                    sc[k] = -1.0f;
                    dirty = true;
                }
            }
        }
        __syncthreads();                               // barrier B
        float Bx = bcast[0], By = bcast[1], Bw = bcast[2], Bh = bcast[3];

        // --- suppression, gated: thread-AABB overlap vs best box ---
        float b1minx = Bx - Bw * 0.5f, b1maxx = Bx + Bw * 0.5f;
        float b1miny = By - Bh * 0.5f, b1maxy = By + Bh * 0.5f;
        bool hit = (b1minx < gmaxx) && (b1maxx > gminx) &&
                   (b1miny < gmaxy) && (b1maxy > gminy);
        if (__any(hit)) {
            float area1 = Bw * Bh;
            #pragma unroll
            for (int k = 0; k < SLOTS; ++k) {
                float4 c = bx[k];
                float dx = Bx - c.x, dy = By - c.y;
                // separating-axis gate: false only when inter==0 -> diou<=0 -> no suppress
                bool nearxy = (fabsf(dx) * 2.0f < (Bw + c.z)) &&
                              (fabsf(dy) * 2.0f < (Bh + c.w));
                if (__any(nearxy)) {
                    // exact round-1 DIoU lines (matched numpy bit-for-bit)
                    float b2minx = c.x - c.z * 0.5f, b2maxx = c.x + c.z * 0.5f;
                    float b2miny = c.y - c.w * 0.5f, b2maxy = c.y + c.w * 0.5f;
                    float iw = fmaxf(fminf(b1maxx, b2maxx) - fmaxf(b1minx, b2minx), 0.f);
                    float ih = fmaxf(fminf(b1maxy, b2maxy) - fmaxf(b1miny, b2miny), 0.f);
                    float inter = iw * ih;
                    float uni   = area1 + c.z * c.w - inter;
                    float iou   = inter / (uni + 1e-9f);
                    float ex = fmaxf(b1maxx, b2maxx) - fminf(b1minx, b2minx);
                    float ey = fmaxf(b1maxy, b2maxy) - fminf(b1miny, b2miny);
                    float c2 = ex * ex + ey * ey + 1e-9f;
                    float diou = iou - (dx * dx + dy * dy) / c2;
                    if (diou > IOU_TH) { sc[k] = -1.0f; dirty = true; }
                }
            }
        }
        // next barrier A separates this iter's bcast/red reads from next iter's writes
    }

    __syncthreads();
    if (tid < NDET * 6) o[tid] = dets[tid];
}

extern "C" void kernel_launch(void* const* d_in, const int* in_sizes, int n_in,
                              void* d_out, int out_size, void* d_ws, size_t ws_size,
                              hipStream_t stream) {
    const float* p0 = (const float*)d_in[0];
    const float* p1 = (const float*)d_in[1];
    const float* p2 = (const float*)d_in[2];
    float* out = (float*)d_out;

    char* ws = (char*)d_ws;
    float4*        boxes   = (float4*)ws;                                  // 4,128,768 B
    float*         scores  = (float*)(ws + (size_t)NB * NANCH * sizeof(float4));
    unsigned char* classes = (unsigned char*)(ws + (size_t)NB * NANCH * (sizeof(float4) + sizeof(float)));

    decode_kernel<<<NB * DEC_BLOCKS_PER_IMG, DEC_THREADS, 0, stream>>>(p0, p1, p2, boxes, scores, classes);
    nms_kernel<<<NB, NMS_THREADS, 0, stream>>>(boxes, scores, classes, out);
}

// Round 3
// 1043.248 us; speedup vs baseline: 1.1440x; 1.1440x over previous
//
#include <hip/hip_runtime.h>
#include <math.h>

#define NANCH 16128      // 64*64*3 + 32*32*3 + 16*16*3
#define NB    16
#define NDET  100
#define SCORE_TH 0.25f
#define IOU_TH   0.5f
#define IMGSZ    512.0f

#define DEC_THREADS 256
#define DEC_ANCH    192               // anchors per decode block (divides 12288/3072/768)
#define DEC_BLOCKS_PER_IMG 84         // 16128 / 192
#define DEC_DW4     (DEC_ANCH * 85 / 4)   // 4080 float4 = 63.75 KB LDS

#define NMS_THREADS 1024
#define SLOTS 16

#define REP16(M) M(0) M(1) M(2) M(3) M(4) M(5) M(6) M(7) \
                 M(8) M(9) M(10) M(11) M(12) M(13) M(14) M(15)

__device__ __constant__ float c_anchors[18] = {
    12.f,16.f, 19.f,36.f, 40.f,28.f,
    36.f,75.f, 76.f,55.f, 72.f,146.f,
    142.f,110.f, 192.f,243.f, 459.f,401.f
};

__device__ __forceinline__ float sigmoidf_(float x) {
    return 1.0f / (1.0f + expf(-x));
}

__global__ __launch_bounds__(DEC_THREADS)
void decode_kernel(const float* __restrict__ p0,
                   const float* __restrict__ p1,
                   const float* __restrict__ p2,
                   float4* __restrict__ boxes,
                   float* __restrict__ scores,
                   unsigned char* __restrict__ classes) {
    __shared__ float4 lds4[DEC_DW4];

    int blk = blockIdx.x;
    int b   = blk / DEC_BLOCKS_PER_IMG;
    int seg = blk % DEC_BLOCKS_PER_IMG;

    const float* src; int S, lgS, scale, loc;
    float stride;
    if (seg < 64)      { scale = 0; S = 64; lgS = 6; stride = 8.f;  src = p0; loc = seg * DEC_ANCH; }
    else if (seg < 80) { scale = 1; S = 32; lgS = 5; stride = 16.f; src = p1; loc = seg * DEC_ANCH - 12288; }
    else               { scale = 2; S = 16; lgS = 4; stride = 32.f; src = p2; loc = seg * DEC_ANCH - 15360; }

    // coalesced float4 staging: base offset is a multiple of 16320 floats -> 16B aligned
    const float4* s4 = (const float4*)(src + ((size_t)b * (S * S * 3) + loc) * 85);
    {
        int j = threadIdx.x;
        #pragma unroll
        for (int r = 0; r < 15; ++r, j += DEC_THREADS) lds4[j] = s4[j];
        if (j < DEC_DW4) lds4[j] = s4[j];
    }
    __syncthreads();

    int t = threadIdx.x;
    if (t < DEC_ANCH) {
        const float* p = (const float*)lds4 + t * 85;   // stride 85 (odd) -> conflict-free
        int local = loc + t;
        int a    = local % 3;
        int cell = local / 3;
        int gj   = cell & (S - 1);
        int gi   = cell >> lgS;

        float tx = p[0], ty = p[1], tw = p[2], th = p[3], tobj = p[4];

        float bestl = p[5];
        int   bc    = 0;
        #pragma unroll 8
        for (int c = 1; c < 80; ++c) {
            float v = p[5 + c];
            if (v > bestl) { bestl = v; bc = c; }
        }

        float bx = ((sigmoidf_(tx) * 2.0f - 0.5f) + (float)gj) * stride;
        float by = ((sigmoidf_(ty) * 2.0f - 0.5f) + (float)gi) * stride;
        float sw = sigmoidf_(tw) * 2.0f; sw = sw * sw;
        float sh = sigmoidf_(th) * 2.0f; sh = sh * sh;
        float aw = c_anchors[scale * 6 + a * 2];
        float ah = c_anchors[scale * 6 + a * 2 + 1];
        float bw = sw * aw;
        float bh = sh * ah;

        bx = fminf(fmaxf(bx, 0.f), IMGSZ);
        by = fminf(fmaxf(by, 0.f), IMGSZ);
        bw = fminf(fmaxf(bw, 0.f), IMGSZ);
        bh = fminf(fmaxf(bh, 0.f), IMGSZ);

        float score = sigmoidf_(tobj) * sigmoidf_(bestl);
        score = (score >= SCORE_TH) ? score : -1.0f;

        size_t g = (size_t)b * NANCH + seg * DEC_ANCH + t;
        boxes[g]   = make_float4(bx, by, bw, bh);
        scores[g]  = score;
        classes[g] = (unsigned char)bc;
    }
}

__global__ __launch_bounds__(NMS_THREADS, 4)   // 4 waves/SIMD min -> 128 VGPR cap
void nms_kernel(const float4* __restrict__ boxes,
                const float*  __restrict__ scores,
                const unsigned char* __restrict__ classes,
                float* __restrict__ out) {
    int b    = blockIdx.x;
    int tid  = threadIdx.x;
    int lane = tid & 63;
    int wave = tid >> 6;

    const float4*        bb = boxes   + (size_t)b * NANCH;
    const float*         ss = scores  + (size_t)b * NANCH;
    const unsigned char* cc = classes + (size_t)b * NANCH;
    float* o = out + (size_t)b * NDET * 6;

    __shared__ unsigned long long red_k[2][16];   // double-buffered wave maxima
    __shared__ float dets[NDET * 6];

    int  base = tid * SLOTS;
    bool own  = (base < NANCH);      // tid < 1008

    // ---- named-scalar state: 16 x (score, box) in REAL registers ----
    #define DECLK(k) float sc##k, px##k, py##k, pw##k, ph##k;
    REP16(DECLK)

    float gminx = 1e30f, gminy = 1e30f, gmaxx = -1e30f, gmaxy = -1e30f;
    #define LOADK(k)                                                          \
        if (own) {                                                            \
            float4 t_ = bb[base + k];                                         \
            px##k = t_.x; py##k = t_.y; pw##k = t_.z; ph##k = t_.w;           \
            sc##k = ss[base + k];                                             \
            if (sc##k > 0.0f) {                                               \
                gminx = fminf(gminx, px##k - pw##k * 0.5f);                   \
                gmaxx = fmaxf(gmaxx, px##k + pw##k * 0.5f);                   \
                gminy = fminf(gminy, py##k - ph##k * 0.5f);                   \
                gmaxy = fmaxf(gmaxy, py##k + ph##k * 0.5f);                   \
            }                                                                 \
        } else {                                                              \
            sc##k = -1.0f; px##k = 0.f; py##k = 0.f; pw##k = 0.f; ph##k = 0.f;\
        }
    REP16(LOADK)

    float v  = 0.0f;    // cached per-thread max (0 = none live)
    int   vi = 0;
    bool  dirty = true;
    int   buf = 0;

    for (int it = 0; it < NDET; ++it) {
        if (dirty) {
            v = 0.0f; vi = 0;
            #define AMAXK(k) if (sc##k > v) { v = sc##k; vi = base + k; }
            REP16(AMAXK)
            dirty = false;
        }
        // (score, ~idx) packed: u64 max == lexicographic (max score, min idx)
        unsigned long long key = (v > 0.0f)
            ? ((unsigned long long)__float_as_uint(v) << 32) |
              (unsigned long long)(0xFFFFFFFFu - (unsigned int)vi)
            : 0ull;

        #pragma unroll
        for (int off = 32; off; off >>= 1) {
            unsigned long long ok = __shfl_xor(key, off);
            if (ok > key) key = ok;
        }
        if (lane == 0) red_k[buf][wave] = key;
        __syncthreads();                       // the ONLY barrier per iteration

        unsigned long long bk = red_k[buf][lane & 15];
        #pragma unroll
        for (int off = 8; off; off >>= 1) {
            unsigned long long ok = __shfl_xor(bk, off);
            if (ok > bk) bk = ok;
        }

        if (bk == 0ull) {                      // nothing left: zero-fill, done
            for (int z = it * 6 + tid; z < NDET * 6; z += NMS_THREADS) dets[z] = 0.0f;
            break;
        }
        float bestV = __uint_as_float((unsigned int)(bk >> 32));
        int   bestI = (int)(0xFFFFFFFFu - (unsigned int)bk);

        // best box: uniform 16B load (boxes immutable, L2-resident) -> no 2nd barrier
        float4 Bb = bb[bestI];
        float Bx = Bb.x, By = Bb.y, Bw = Bb.z, Bh = Bb.w;

        if (tid == 0) {
            dets[it * 6 + 0] = Bx;
            dets[it * 6 + 1] = By;
            dets[it * 6 + 2] = Bw;
            dets[it * 6 + 3] = Bh;
            dets[it * 6 + 4] = bestV;
            dets[it * 6 + 5] = (float)cc[bestI];
        }

        // owner clears the picked slot (.at[i].set(-1))
        #define CLRBK(k) if (base + k == bestI) { sc##k = -1.0f; dirty = true; }
        REP16(CLRBK)

        // ---- suppression, AABB-gated per thread ----
        float b1minx = Bx - Bw * 0.5f, b1maxx = Bx + Bw * 0.5f;
        float b1miny = By - Bh * 0.5f, b1maxy = By + Bh * 0.5f;
        float area1  = Bw * Bh;
        if (b1minx < gmaxx && b1maxx > gminx && b1miny < gmaxy && b1maxy > gminy) {
            // separating-axis gate: false only when inter==0 -> diou<=0 -> no suppress
            #define SUPPK(k) {                                                        \
                float dx_ = Bx - px##k, dy_ = By - py##k;                             \
                if (fabsf(dx_) * 2.0f < (Bw + pw##k) &&                               \
                    fabsf(dy_) * 2.0f < (Bh + ph##k)) {                               \
                    float b2minx = px##k - pw##k * 0.5f, b2maxx = px##k + pw##k * 0.5f;\
                    float b2miny = py##k - ph##k * 0.5f, b2maxy = py##k + ph##k * 0.5f;\
                    float iw = fmaxf(fminf(b1maxx, b2maxx) - fmaxf(b1minx, b2minx), 0.f);\
                    float ih = fmaxf(fminf(b1maxy, b2maxy) - fmaxf(b1miny, b2miny), 0.f);\
                    float inter = iw * ih;                                            \
                    float uni   = area1 + pw##k * ph##k - inter;                      \
                    float iou   = inter / (uni + 1e-9f);                              \
                    float ex = fmaxf(b1maxx, b2maxx) - fminf(b1minx, b2minx);         \
                    float ey = fmaxf(b1maxy, b2maxy) - fminf(b1miny, b2miny);         \
                    float c2 = ex * ex + ey * ey + 1e-9f;                             \
                    float diou = iou - (dx_ * dx_ + dy_ * dy_) / c2;                  \
                    if (diou > IOU_TH) { sc##k = -1.0f; dirty = true; }               \
                } }
            REP16(SUPPK)
        }
        buf ^= 1;   // double-buffer: next iter's red_k writes can't race this iter's reads
    }

    __syncthreads();
    if (tid < NDET * 6) o[tid] = dets[tid];
}

extern "C" void kernel_launch(void* const* d_in, const int* in_sizes, int n_in,
                              void* d_out, int out_size, void* d_ws, size_t ws_size,
                              hipStream_t stream) {
    const float* p0 = (const float*)d_in[0];
    const float* p1 = (const float*)d_in[1];
    const float* p2 = (const float*)d_in[2];
    float* out = (float*)d_out;

    char* ws = (char*)d_ws;
    float4*        boxes   = (float4*)ws;                                  // 4,128,768 B
    float*         scores  = (float*)(ws + (size_t)NB * NANCH * sizeof(float4));
    unsigned char* classes = (unsigned char*)(ws + (size_t)NB * NANCH * (sizeof(float4) + sizeof(float)));

    decode_kernel<<<NB * DEC_BLOCKS_PER_IMG, DEC_THREADS, 0, stream>>>(p0, p1, p2, boxes, scores, classes);
    nms_kernel<<<NB, NMS_THREADS, 0, stream>>>(boxes, scores, classes, out);
}

// Round 4
// 109.328 us; speedup vs baseline: 10.9166x; 9.5424x over previous
//
#include <hip/hip_runtime.h>
#include <math.h>

#define NANCH 16128      // 64*64*3 + 32*32*3 + 16*16*3
#define NB    16
#define NDET  100
#define SCORE_TH 0.25f
#define IOU_TH   0.5f
#define IMGSZ    512.0f

#define DEC_THREADS 256
#define DEC_ANCH    192               // anchors per decode block (divides 12288/3072/768)
#define DEC_BLOCKS_PER_IMG 84         // 16128 / 192
#define DEC_DW4     (DEC_ANCH * 85 / 4)   // 4080 float4 = 63.75 KB LDS

#define NMS_THREADS 1024
#define KCAP  2048       // candidate key buffer (u64) in LDS
#define NHIST 512
#define SEL_TARGET 512u

__device__ __constant__ float c_anchors[18] = {
    12.f,16.f, 19.f,36.f, 40.f,28.f,
    36.f,75.f, 76.f,55.f, 72.f,146.f,
    142.f,110.f, 192.f,243.f, 459.f,401.f
};

__device__ __forceinline__ float sigmoidf_(float x) {
    return 1.0f / (1.0f + expf(-x));
}

// Exact DIoU suppression test; roles: (B*) = picked/accepted box, (c*) = candidate.
// Float expression order identical to the validated round-1/3 kernels (absmax 0).
__device__ __forceinline__ bool suppresses(float Bx, float By, float Bw, float Bh,
                                           float cx, float cy, float cw, float ch) {
    float b1minx = Bx - Bw * 0.5f, b1maxx = Bx + Bw * 0.5f;
    float b1miny = By - Bh * 0.5f, b1maxy = By + Bh * 0.5f;
    float b2minx = cx - cw * 0.5f, b2maxx = cx + cw * 0.5f;
    float b2miny = cy - ch * 0.5f, b2maxy = cy + ch * 0.5f;
    float iw = fmaxf(fminf(b1maxx, b2maxx) - fmaxf(b1minx, b2minx), 0.f);
    float ih = fmaxf(fminf(b1maxy, b2maxy) - fmaxf(b1miny, b2miny), 0.f);
    float inter = iw * ih;
    float uni   = Bw * Bh + cw * ch - inter;
    float iou   = inter / (uni + 1e-9f);
    float ex = fmaxf(b1maxx, b2maxx) - fminf(b1minx, b2minx);
    float ey = fmaxf(b1maxy, b2maxy) - fminf(b1miny, b2miny);
    float c2 = ex * ex + ey * ey + 1e-9f;
    float dx = Bx - cx, dy = By - cy;
    float diou = iou - (dx * dx + dy * dy) / c2;
    return diou > IOU_TH;
}

__global__ __launch_bounds__(DEC_THREADS)
void decode_kernel(const float* __restrict__ p0,
                   const float* __restrict__ p1,
                   const float* __restrict__ p2,
                   float4* __restrict__ boxes,
                   float* __restrict__ scores,
                   unsigned char* __restrict__ classes) {
    __shared__ float4 lds4[DEC_DW4];

    int blk = blockIdx.x;
    int b   = blk / DEC_BLOCKS_PER_IMG;
    int seg = blk % DEC_BLOCKS_PER_IMG;

    const float* src; int S, lgS, scale, loc;
    float stride;
    if (seg < 64)      { scale = 0; S = 64; lgS = 6; stride = 8.f;  src = p0; loc = seg * DEC_ANCH; }
    else if (seg < 80) { scale = 1; S = 32; lgS = 5; stride = 16.f; src = p1; loc = seg * DEC_ANCH - 12288; }
    else               { scale = 2; S = 16; lgS = 4; stride = 32.f; src = p2; loc = seg * DEC_ANCH - 15360; }

    const float4* s4 = (const float4*)(src + ((size_t)b * (S * S * 3) + loc) * 85);
    {
        int j = threadIdx.x;
        #pragma unroll
        for (int r = 0; r < 15; ++r, j += DEC_THREADS) lds4[j] = s4[j];
        if (j < DEC_DW4) lds4[j] = s4[j];
    }
    __syncthreads();

    int t = threadIdx.x;
    if (t < DEC_ANCH) {
        const float* p = (const float*)lds4 + t * 85;   // stride 85 (odd) -> conflict-free
        int local = loc + t;
        int a    = local % 3;
        int cell = local / 3;
        int gj   = cell & (S - 1);
        int gi   = cell >> lgS;

        float tx = p[0], ty = p[1], tw = p[2], th = p[3], tobj = p[4];

        float bestl = p[5];
        int   bc    = 0;
        #pragma unroll 8
        for (int c = 1; c < 80; ++c) {
            float v = p[5 + c];
            if (v > bestl) { bestl = v; bc = c; }
        }

        float bx = ((sigmoidf_(tx) * 2.0f - 0.5f) + (float)gj) * stride;
        float by = ((sigmoidf_(ty) * 2.0f - 0.5f) + (float)gi) * stride;
        float sw = sigmoidf_(tw) * 2.0f; sw = sw * sw;
        float sh = sigmoidf_(th) * 2.0f; sh = sh * sh;
        float aw = c_anchors[scale * 6 + a * 2];
        float ah = c_anchors[scale * 6 + a * 2 + 1];
        float bw = sw * aw;
        float bh = sh * ah;

        bx = fminf(fmaxf(bx, 0.f), IMGSZ);
        by = fminf(fmaxf(by, 0.f), IMGSZ);
        bw = fminf(fmaxf(bw, 0.f), IMGSZ);
        bh = fminf(fmaxf(bh, 0.f), IMGSZ);

        float score = sigmoidf_(tobj) * sigmoidf_(bestl);
        score = (score >= SCORE_TH) ? score : -1.0f;

        size_t g = (size_t)b * NANCH + seg * DEC_ANCH + t;
        boxes[g]   = make_float4(bx, by, bw, bh);
        scores[g]  = score;
        classes[g] = (unsigned char)bc;
    }
}

// One block per image. Histogram-select top prefix -> bitonic sort -> ordered scan.
__global__ __launch_bounds__(NMS_THREADS)
void nms_kernel(const float4* __restrict__ boxes,
                const float*  __restrict__ scores,
                const unsigned char* __restrict__ classes,
                float* __restrict__ out) {
    int b    = blockIdx.x;
    int tid  = threadIdx.x;
    int lane = tid & 63;
    int wave = tid >> 6;

    const float4*        bb = boxes   + (size_t)b * NANCH;
    const float*         ss = scores  + (size_t)b * NANCH;
    const unsigned char* cc = classes + (size_t)b * NANCH;
    float* o = out + (size_t)b * NDET * 6;

    __shared__ unsigned int       hist[NHIST];
    __shared__ unsigned long long keyb[KCAP];
    __shared__ float4             acc[NDET];
    __shared__ float              dets[NDET * 6];
    __shared__ int                ctrl[4];   // 0: nsel, 1: A(accepted), 2: bstar, 3: remaining

    if (tid < NHIST) hist[tid] = 0u;
    if (tid < 4) ctrl[tid] = 0;
    __syncthreads();

    // ---- histogram of score buckets (coalesced reads) ----
    #pragma unroll
    for (int k = 0; k < NANCH / NMS_THREADS + 1; ++k) {
        int i = tid + k * NMS_THREADS;
        if (i < NANCH) {
            float s = ss[i];
            if (s > 0.0f) {
                int bk = (int)(__float_as_uint(s) >> 15) - 32000;   // [0,512), monotone in s
                atomicAdd(&hist[bk], 1u);
            }
        }
    }
    __syncthreads();

    int b_hi = NHIST;    // exclusive upper bucket bound of not-yet-processed candidates

    for (int round = 0; round < 64; ++round) {
        // ---- threshold selection (wave 0): largest b* with suffixcount >= SEL_TARGET ----
        if (wave == 0) {
            int b0 = lane * 8;
            unsigned int seg = 0;
            #pragma unroll
            for (int j = 0; j < 8; ++j) { int bu = b0 + j; if (bu < b_hi) seg += hist[bu]; }
            unsigned int suf = seg;                       // inclusive suffix over lanes >= l
            #pragma unroll
            for (int off = 1; off < 64; off <<= 1) {
                unsigned int ov = __shfl_down(suf, off);
                if (lane + off < 64) suf += ov;
            }
            unsigned int remaining = __shfl(suf, 0);
            int bstar;
            if (remaining == 0u)            bstar = b_hi;
            else if (remaining <= (unsigned)KCAP) bstar = 0;
            else {
                unsigned int above = (lane == 63) ? 0u : __shfl_down(suf, 1);
                unsigned int run = above;
                int loc = -1; unsigned int locS = 0;
                #pragma unroll
                for (int j = 7; j >= 0; --j) {
                    int bu = b0 + j;
                    if (bu < b_hi) {
                        run += hist[bu];
                        if (loc < 0 && run >= SEL_TARGET) { loc = bu; locS = run; }
                    }
                }
                unsigned long long pk = (loc < 0) ? 0ull
                    : (((unsigned long long)(loc + 1) << 32) | (unsigned long long)locS);
                #pragma unroll
                for (int off = 32; off; off >>= 1) {
                    unsigned long long op = __shfl_xor(pk, off);
                    if (op > pk) pk = op;
                }
                bstar = (int)(pk >> 32) - 1;
                unsigned int selS = (unsigned int)pk;
                if (selS > (unsigned)KCAP) bstar += 1;   // exact smaller prefix; continuation handles rest
            }
            if (lane == 0) { ctrl[0] = 0; ctrl[2] = bstar; ctrl[3] = (int)remaining; }
        }
        __syncthreads();

        int bstar     = ctrl[2];
        int remaining = ctrl[3];
        int A0        = ctrl[1];
        if (remaining == 0 || A0 >= NDET) break;     // uniform exit

        // ---- compact selected keys (bucket in [bstar, b_hi)) ----
        #pragma unroll
        for (int k = 0; k < NANCH / NMS_THREADS + 1; ++k) {
            int i = tid + k * NMS_THREADS;
            if (i < NANCH) {
                float s = ss[i];
                if (s > 0.0f) {
                    int bk = (int)(__float_as_uint(s) >> 15) - 32000;
                    if (bk >= bstar && bk < b_hi) {
                        int pos = atomicAdd(&ctrl[0], 1);
                        if (pos < KCAP) {
                            keyb[pos] = ((unsigned long long)__float_as_uint(s) << 32)
                                      | (unsigned long long)(0xFFFFFFFFu - (unsigned int)i);
                        }
                    }
                }
            }
        }
        __syncthreads();

        int nsel = ctrl[0]; if (nsel > KCAP) nsel = KCAP;
        if (nsel > 0) {
            int N = 1; while (N < nsel) N <<= 1;

            // pad [nsel, N) with 0 (sorts to the bottom of ascending order)
            for (int t2 = tid; t2 < N; t2 += NMS_THREADS)
                if (t2 >= nsel) keyb[t2] = 0ull;

            // ---- bitonic sort ascending; real keys end up in [N-nsel, N) ----
            for (int k2 = 2; k2 <= N; k2 <<= 1) {
                for (int j2 = k2 >> 1; j2 > 0; j2 >>= 1) {
                    __syncthreads();
                    for (int t2 = tid; t2 < N; t2 += NMS_THREADS) {
                        int p2 = t2 ^ j2;
                        if (p2 > t2) {
                            unsigned long long av = keyb[t2], bv = keyb[p2];
                            bool up = ((t2 & k2) == 0);
                            if (up ? (av > bv) : (av < bv)) { keyb[t2] = bv; keyb[p2] = av; }
                        }
                    }
                }
            }
            __syncthreads();

            // ---- ordered greedy scan (wave 0 only) ----
            if (wave == 0) {
                int A = ctrl[1];
                for (int sb = N - 1; sb >= 0 && A < NDET; sb -= 64) {
                    int pos = sb - lane;                       // lane 0 = highest key
                    bool valid = (pos >= N - nsel) && (pos >= 0);
                    unsigned long long key = valid ? keyb[pos] : 0ull;
                    valid = valid && (key != 0ull);
                    unsigned int idx = 0xFFFFFFFFu - (unsigned int)key;
                    float scv = __uint_as_float((unsigned int)(key >> 32));
                    float4 c = make_float4(0.f, 0.f, 0.f, 0.f);
                    if (valid) c = bb[idx];
                    bool alive = valid;
                    for (int i = 0; i < A; ++i) {              // pre-check vs accepted
                        float4 a = acc[i];
                        if (alive && suppresses(a.x, a.y, a.z, a.w, c.x, c.y, c.z, c.w))
                            alive = false;
                    }
                    unsigned long long m = __ballot(alive);
                    while (m && A < NDET) {
                        int l = (int)__builtin_ctzll(m);       // highest-key surviving lane
                        float Bx = __shfl(c.x, l), By = __shfl(c.y, l);
                        float Bw = __shfl(c.z, l), Bh = __shfl(c.w, l);
                        if (lane == l) {
                            acc[A] = c;
                            dets[A * 6 + 0] = c.x;
                            dets[A * 6 + 1] = c.y;
                            dets[A * 6 + 2] = c.z;
                            dets[A * 6 + 3] = c.w;
                            dets[A * 6 + 4] = scv;
                            dets[A * 6 + 5] = (float)cc[idx];
                        }
                        A++;
                        if (lane == l) alive = false;
                        else if (alive && lane > l &&
                                 suppresses(Bx, By, Bw, Bh, c.x, c.y, c.z, c.w))
                            alive = false;
                        m = __ballot(alive);
                    }
                }
                if (lane == 0) ctrl[1] = A;
            }
        }
        __syncthreads();
        if (bstar >= b_hi) break;    // no progress possible (pathological) -> stop
        b_hi = bstar;
    }

    __syncthreads();
    int A = ctrl[1];
    for (int i = tid; i < NDET * 6; i += NMS_THREADS)
        if (i >= A * 6) dets[i] = 0.0f;
    __syncthreads();
    if (tid < NDET * 6) o[tid] = dets[tid];
}

extern "C" void kernel_launch(void* const* d_in, const int* in_sizes, int n_in,
                              void* d_out, int out_size, void* d_ws, size_t ws_size,
                              hipStream_t stream) {
    const float* p0 = (const float*)d_in[0];
    const float* p1 = (const float*)d_in[1];
    const float* p2 = (const float*)d_in[2];
    float* out = (float*)d_out;

    char* ws = (char*)d_ws;
    float4*        boxes   = (float4*)ws;                                  // 4,128,768 B
    float*         scores  = (float*)(ws + (size_t)NB * NANCH * sizeof(float4));
    unsigned char* classes = (unsigned char*)(ws + (size_t)NB * NANCH * (sizeof(float4) + sizeof(float)));

    decode_kernel<<<NB * DEC_BLOCKS_PER_IMG, DEC_THREADS, 0, stream>>>(p0, p1, p2, boxes, scores, classes);
    nms_kernel<<<NB, NMS_THREADS, 0, stream>>>(boxes, scores, classes, out);
}

// Round 5
// 99.572 us; speedup vs baseline: 11.9861x; 1.0980x over previous
//
#include <hip/hip_runtime.h>
#include <math.h>

#define NANCH 16128      // 64*64*3 + 32*32*3 + 16*16*3
#define NSEG  84         // decode segments per image
#define SEGA  192        // anchors per segment
#define NB    16
#define NDET  100
#define SCORE_TH 0.25f
#define IOU_TH   0.5f
#define IMGSZ    512.0f

#define DEC_THREADS 256
#define DEC_DW4     (SEGA * 85 / 4)   // 4080 float4 = 63.75 KB LDS

#define NMS_THREADS 512
#define KCAP   2048
#define NHIST  512
#define SEL_TARGET 256u
#define FASTCAP 512

__device__ __constant__ float c_anchors[18] = {
    12.f,16.f, 19.f,36.f, 40.f,28.f,
    36.f,75.f, 76.f,55.f, 72.f,146.f,
    142.f,110.f, 192.f,243.f, 459.f,401.f
};

__device__ __forceinline__ float sigmoidf_(float x) {
    return 1.0f / (1.0f + expf(-x));
}

// Exact DIoU suppression test; roles: (B*) = accepted box, (c*) = candidate.
// Float expression order identical to the validated round-1..4 kernels (absmax 0).
__device__ __forceinline__ bool suppresses(float Bx, float By, float Bw, float Bh,
                                           float cx, float cy, float cw, float ch) {
    float b1minx = Bx - Bw * 0.5f, b1maxx = Bx + Bw * 0.5f;
    float b1miny = By - Bh * 0.5f, b1maxy = By + Bh * 0.5f;
    float b2minx = cx - cw * 0.5f, b2maxx = cx + cw * 0.5f;
    float b2miny = cy - ch * 0.5f, b2maxy = cy + ch * 0.5f;
    float iw = fmaxf(fminf(b1maxx, b2maxx) - fmaxf(b1minx, b2minx), 0.f);
    float ih = fmaxf(fminf(b1maxy, b2maxy) - fmaxf(b1miny, b2miny), 0.f);
    float inter = iw * ih;
    float uni   = Bw * Bh + cw * ch - inter;
    float iou   = inter / (uni + 1e-9f);
    float ex = fmaxf(b1maxx, b2maxx) - fminf(b1minx, b2minx);
    float ey = fmaxf(b1maxy, b2maxy) - fminf(b1miny, b2miny);
    float c2 = ex * ex + ey * ey + 1e-9f;
    float dx = Bx - cx, dy = By - cy;
    float diou = iou - (dx * dx + dy * dy) / c2;
    return diou > IOU_TH;
}

// key layout: [score_bits:32][16383-idx:14][class:7][0:11]
// u64 ascending order == (score asc, idx desc) -> max = (max score, min idx).

__global__ __launch_bounds__(DEC_THREADS)
void decode_kernel(const float* __restrict__ p0,
                   const float* __restrict__ p1,
                   const float* __restrict__ p2,
                   float4* __restrict__ boxes,
                   unsigned long long* __restrict__ keylist,
                   int* __restrict__ counts) {
    __shared__ float4 lds4[DEC_DW4];
    __shared__ int wcnt[4];

    int blk = blockIdx.x;
    int b   = blk / NSEG;
    int seg = blk - b * NSEG;

    const float* src; int S, lgS, scale, loc;
    float stride;
    if (seg < 64)      { scale = 0; S = 64; lgS = 6; stride = 8.f;  src = p0; loc = seg * SEGA; }
    else if (seg < 80) { scale = 1; S = 32; lgS = 5; stride = 16.f; src = p1; loc = seg * SEGA - 12288; }
    else               { scale = 2; S = 16; lgS = 4; stride = 32.f; src = p2; loc = seg * SEGA - 15360; }

    // coalesced float4 staging (base multiple of 16320 floats -> 16B aligned)
    const float4* s4 = (const float4*)(src + ((size_t)b * (S * S * 3) + loc) * 85);
    {
        int j = threadIdx.x;
        #pragma unroll
        for (int r = 0; r < 15; ++r, j += DEC_THREADS) lds4[j] = s4[j];
        if (j < DEC_DW4) lds4[j] = s4[j];
    }
    __syncthreads();

    int t = threadIdx.x;
    bool cand = false;
    unsigned long long key = 0ull;
    if (t < SEGA) {
        const float* p = (const float*)lds4 + t * 85;   // stride 85 (odd) -> conflict-free
        int local = loc + t;
        int a    = local % 3;
        int cell = local / 3;
        int gj   = cell & (S - 1);
        int gi   = cell >> lgS;

        float tx = p[0], ty = p[1], tw = p[2], th = p[3], tobj = p[4];

        float bestl = p[5];
        int   bc    = 0;
        #pragma unroll 8
        for (int c = 1; c < 80; ++c) {
            float v = p[5 + c];
            if (v > bestl) { bestl = v; bc = c; }
        }

        float bx = ((sigmoidf_(tx) * 2.0f - 0.5f) + (float)gj) * stride;
        float by = ((sigmoidf_(ty) * 2.0f - 0.5f) + (float)gi) * stride;
        float sw = sigmoidf_(tw) * 2.0f; sw = sw * sw;
        float sh = sigmoidf_(th) * 2.0f; sh = sh * sh;
        float aw = c_anchors[scale * 6 + a * 2];
        float ah = c_anchors[scale * 6 + a * 2 + 1];
        float bw = sw * aw;
        float bh = sh * ah;

        bx = fminf(fmaxf(bx, 0.f), IMGSZ);
        by = fminf(fmaxf(by, 0.f), IMGSZ);
        bw = fminf(fmaxf(bw, 0.f), IMGSZ);
        bh = fminf(fmaxf(bh, 0.f), IMGSZ);

        float score = sigmoidf_(tobj) * sigmoidf_(bestl);
        if (score >= SCORE_TH) {
            cand = true;
            int gidx = seg * SEGA + t;
            boxes[(size_t)b * NANCH + gidx] = make_float4(bx, by, bw, bh);
            key = ((unsigned long long)__float_as_uint(score) << 32)
                | ((unsigned long long)(16383 - gidx) << 18)
                | ((unsigned long long)bc << 11);
        }
    }

    // per-wave ballot compaction into the segment's key slots
    unsigned long long m = __ballot(cand);
    int lane = t & 63, w = t >> 6;
    if (lane == 0) wcnt[w] = __popcll(m);
    __syncthreads();
    int base = 0;
    #pragma unroll
    for (int j = 0; j < 4; ++j) if (j < w) base += wcnt[j];
    if (cand) {
        int pos = base + __popcll(m & ((1ull << lane) - 1ull));
        keylist[(size_t)b * NANCH + seg * SEGA + pos] = key;
    }
    if (t == 0) counts[b * NSEG + seg] = wcnt[0] + wcnt[1] + wcnt[2] + wcnt[3];
}

// One block (512 thr) per image: hist -> threshold -> compact -> hybrid sort -> ordered scan.
__global__ __launch_bounds__(NMS_THREADS)
void nms_kernel(const float4* __restrict__ boxes,
                const unsigned long long* __restrict__ keylist,
                const int* __restrict__ counts,
                float* __restrict__ out) {
    int b    = blockIdx.x;
    int tid  = threadIdx.x;
    int lane = tid & 63;
    int wave = tid >> 6;

    const float4* bb = boxes + (size_t)b * NANCH;
    const unsigned long long* kl = keylist + (size_t)b * NANCH;
    float* o = out + (size_t)b * NDET * 6;

    __shared__ unsigned int       hist[NHIST];
    __shared__ unsigned long long keyb[KCAP];
    __shared__ int                cnts[NSEG];
    __shared__ float4             acc[NDET];
    __shared__ float              dets[NDET * 6];
    __shared__ int                ctrl[2];   // 0: nsel counter, 1: A accepted

    if (tid < NHIST) hist[tid] = 0u;
    if (tid < NSEG)  cnts[tid] = counts[b * NSEG + tid];
    if (tid < 2)     ctrl[tid] = 0;
    __syncthreads();

    // ---- histogram over candidate keys (segmented traversal, 8 waves) ----
    for (int s = wave; s < NSEG; s += 8) {
        int cnt = cnts[s];
        const unsigned long long* segp = kl + s * SEGA;
        for (int j = lane; j < cnt; j += 64) {
            int bu = (int)(segp[j] >> 47) - 32000;   // [0,512), monotone in score
            atomicAdd(&hist[bu], 1u);
        }
    }
    __syncthreads();

    int b_hi = NHIST;
    for (int round = 0; round < 64; ++round) {
        if (tid == 0) ctrl[0] = 0;

        // ---- threshold select, computed redundantly by every wave ----
        int b0 = lane * 8;
        unsigned int segsum = 0;
        #pragma unroll
        for (int j = 0; j < 8; ++j) { int bu = b0 + j; if (bu < b_hi) segsum += hist[bu]; }
        unsigned int suf = segsum;                  // inclusive suffix over lanes >= l
        #pragma unroll
        for (int off = 1; off < 64; off <<= 1) {
            unsigned int ov = __shfl_down(suf, off);
            if (lane + off < 64) suf += ov;
        }
        unsigned int remaining = __shfl(suf, 0);
        int A0 = ctrl[1];
        if (remaining == 0u || A0 >= NDET) break;   // uniform exit

        int bstar;
        if (remaining <= (unsigned)FASTCAP) bstar = 0;
        else {
            unsigned int above = (lane == 63) ? 0u : __shfl_down(suf, 1);
            unsigned int run = above;
            int loc = -1; unsigned int locS = 0, locAb = 0;
            #pragma unroll
            for (int j = 7; j >= 0; --j) {
                int bu = b0 + j;
                if (bu < b_hi) {
                    unsigned int prev = run;
                    run += hist[bu];
                    if (loc < 0 && run >= SEL_TARGET) { loc = bu; locS = run; locAb = prev; }
                }
            }
            unsigned long long pk = (loc < 0) ? 0ull
                : (((unsigned long long)(loc + 1) << 32)
                   | ((unsigned long long)locAb << 1)
                   | (unsigned long long)(locS > (unsigned)FASTCAP ? 1u : 0u));
            #pragma unroll
            for (int off = 32; off; off >>= 1) {
                unsigned long long op = __shfl_xor(pk, off);
                if (op > pk) pk = op;
            }
            int loc2 = (int)(pk >> 32) - 1;
            bool fat = (pk & 1ull) != 0ull;
            unsigned int above2 = (unsigned int)((pk >> 1) & 0x7FFFFFFFull);
            // fat bucket: take only the part above it (continuation handles it),
            // unless it's the very top of the remaining range -> must process it now.
            bstar = (fat && above2 > 0u) ? loc2 + 1 : loc2;
        }
        __syncthreads();   // protects ctrl[0] reset + keyb reuse

        // ---- compact keys with bucket in [bstar, b_hi), wave-aggregated ----
        for (int s = wave; s < NSEG; s += 8) {
            int cnt = cnts[s];
            const unsigned long long* segp = kl + s * SEGA;
            for (int j0 = 0; j0 < cnt; j0 += 64) {
                int j = j0 + lane;
                unsigned long long key = 0ull;
                bool pass = false;
                if (j < cnt) {
                    key = segp[j];
                    int bu = (int)(key >> 47) - 32000;
                    pass = (bu >= bstar && bu < b_hi);
                }
                unsigned long long m = __ballot(pass);
                if (m) {
                    int basep;
                    if (lane == 0) basep = atomicAdd(&ctrl[0], (int)__popcll(m));
                    basep = __shfl(basep, 0);
                    if (pass) {
                        int pos = basep + (int)__popcll(m & ((1ull << lane) - 1ull));
                        if (pos < KCAP) keyb[pos] = key;
                    }
                }
            }
        }
        __syncthreads();

        int nsel = ctrl[0]; if (nsel > KCAP) nsel = KCAP;
        int N = 64; while (N < nsel) N <<= 1;

        if (nsel > 0) {
            if (nsel <= FASTCAP) {
                // ---- hybrid bitonic: 1 elem/thread, shfl for j2<64 (no barriers) ----
                unsigned long long v = (tid < nsel) ? keyb[tid] : 0ull;
                for (int k2 = 2; k2 <= N; k2 <<= 1) {
                    for (int j2 = k2 >> 1; j2 > 0; j2 >>= 1) {
                        unsigned long long pv;
                        if (j2 < 64) {
                            pv = __shfl_xor(v, j2);
                        } else {
                            __syncthreads();
                            keyb[tid] = v;
                            __syncthreads();
                            pv = keyb[tid ^ j2];
                        }
                        bool dir     = ((tid & k2) == 0);
                        bool keepmin = (((tid & j2) == 0) == dir);
                        bool take    = keepmin ? (pv < v) : (pv > v);
                        if (take) v = pv;
                    }
                }
                __syncthreads();
                keyb[tid] = v;
                __syncthreads();
            } else {
                // ---- general LDS bitonic fallback (rare: fat-bucket case) ----
                for (int t2 = tid; t2 < N; t2 += NMS_THREADS)
                    if (t2 >= nsel) keyb[t2] = 0ull;
                for (int k2 = 2; k2 <= N; k2 <<= 1) {
                    for (int j2 = k2 >> 1; j2 > 0; j2 >>= 1) {
                        __syncthreads();
                        for (int t2 = tid; t2 < N; t2 += NMS_THREADS) {
                            int p2 = t2 ^ j2;
                            if (p2 > t2) {
                                unsigned long long av = keyb[t2], bv = keyb[p2];
                                bool up = ((t2 & k2) == 0);
                                if (up ? (av > bv) : (av < bv)) { keyb[t2] = bv; keyb[p2] = av; }
                            }
                        }
                    }
                }
                __syncthreads();
            }

            // ---- ordered greedy scan (wave 0) ----
            if (wave == 0) {
                int A = ctrl[1];
                for (int sb = N - 1; sb >= 0 && A < NDET; sb -= 64) {
                    int pos = sb - lane;                    // lane 0 = highest key
                    bool valid = (pos >= N - nsel) && (pos >= 0);
                    unsigned long long key = valid ? keyb[pos] : 0ull;
                    valid = valid && (key != 0ull);
                    int   idx = 16383 - (int)((key >> 18) & 0x3FFFull);
                    float scv = __uint_as_float((unsigned int)(key >> 32));
                    float cls = (float)((key >> 11) & 0x7Full);
                    float4 c = make_float4(0.f, 0.f, 0.f, 0.f);
                    if (valid) c = bb[idx];
                    bool alive = valid;
                    for (int i = 0; i < A; ++i) {           // pre-check vs accepted
                        float4 a = acc[i];
                        if (alive && suppresses(a.x, a.y, a.z, a.w, c.x, c.y, c.z, c.w))
                            alive = false;
                    }
                    unsigned long long mm = __ballot(alive);
                    while (mm && A < NDET) {
                        int l = (int)__builtin_ctzll(mm);   // highest-key survivor
                        float Bx = __shfl(c.x, l), By = __shfl(c.y, l);
                        float Bw = __shfl(c.z, l), Bh = __shfl(c.w, l);
                        if (lane == l) {
                            acc[A] = c;
                            dets[A * 6 + 0] = c.x;
                            dets[A * 6 + 1] = c.y;
                            dets[A * 6 + 2] = c.z;
                            dets[A * 6 + 3] = c.w;
                            dets[A * 6 + 4] = scv;
                            dets[A * 6 + 5] = cls;
                            alive = false;
                        }
                        A++;
                        if (alive && lane > l &&
                            suppresses(Bx, By, Bw, Bh, c.x, c.y, c.z, c.w))
                            alive = false;
                        mm = __ballot(alive);
                    }
                }
                if (lane == 0) ctrl[1] = A;
            }
        }
        __syncthreads();
        if (bstar >= b_hi) break;    // safety (unreachable by construction)
        b_hi = bstar;
    }

    __syncthreads();
    int A = ctrl[1];
    for (int i = tid; i < NDET * 6; i += NMS_THREADS)
        if (i >= A * 6) dets[i] = 0.0f;
    __syncthreads();
    for (int i = tid; i < NDET * 6; i += NMS_THREADS) o[i] = dets[i];
}

extern "C" void kernel_launch(void* const* d_in, const int* in_sizes, int n_in,
                              void* d_out, int out_size, void* d_ws, size_t ws_size,
                              hipStream_t stream) {
    const float* p0 = (const float*)d_in[0];
    const float* p1 = (const float*)d_in[1];
    const float* p2 = (const float*)d_in[2];
    float* out = (float*)d_out;

    char* ws = (char*)d_ws;
    float4*             boxes   = (float4*)ws;                                   // 4,128,768 B
    unsigned long long* keylist = (unsigned long long*)(ws + (size_t)NB * NANCH * sizeof(float4));
    int*                counts  = (int*)(ws + (size_t)NB * NANCH * (sizeof(float4) + sizeof(unsigned long long)));

    decode_kernel<<<NB * NSEG, DEC_THREADS, 0, stream>>>(p0, p1, p2, boxes, keylist, counts);
    nms_kernel<<<NB, NMS_THREADS, 0, stream>>>(boxes, keylist, counts, out);
}